// Round 15
// baseline (395.456 us; speedup 1.0000x reference)
//
#include <hip/hip_runtime.h>

typedef __attribute__((ext_vector_type(8))) short short8;
typedef __attribute__((ext_vector_type(4))) float float4v;

#define NLAGS 9
#define HID 256
#define GSAMP 16
#define NTHREADS 1024      // 16 waves/block, ONE column per wave (r12 body)
#define NGRP 8             // persistent: 8 sample-groups per block
#define NBLK 256           // 256 x 8 x 16 = 32768 samples
// sT (36864 sh) + scratch 256 f32 (512 sh) + scratch2 2x144 f32 (576 sh)
#define SBUF_SHORTS (36864 + 512 + 576)   // 75,904 B

// LUT geometry: 9 rows (per lag-slot d), 2048 knots over [-8, 8]
#define NK 2048
#define LUT_STRIDE 2056                   // padded row stride (floats)
#define SLO -8.0f
#define KINV 128.0f                       // NK / 16

union S8 { short8 v; unsigned short u[8]; };

__device__ __forceinline__ unsigned short f2b(float f) {
  union { float f; unsigned int i; } c; c.f = f;
  return (unsigned short)((c.i + 0x7FFFu + ((c.i >> 16) & 1u)) >> 16);  // RNE
}
__device__ __forceinline__ float sane(float x) {
  return (__builtin_isfinite(x) && fabsf(x) < 1e30f) ? x : 0.0f;
}
// HW packed f32->bf16 (RNE), 1 VALU op for 2 conversions
__device__ __forceinline__ unsigned int pkbf16(float lo, float hi) {
  unsigned int r;
  asm("v_cvt_pk_bf16_f32 %0, %1, %2" : "=v"(r) : "v"(lo), "v"(hi));
  return r;
}
// unclamped tanh: exp->0 gives -1, exp->inf gives +1; finite-in => finite-out
// BLACKLIST (r8-r10 bisect): bias-init-in-MFMA-C and exp2f-tanh broke correctness.
// BLACKLIST (R10): hipLaunchCooperativeKernel -> silent non-exec under capture.
// REGISTER/OCCUPANCY MODEL (R1-R6): occupancy = floor(512/(arch+agpr)) per SIMD;
//   spill iff arch demand > compiler cap. R11 NOISE: +-10-15us run to run.
// R12/R13: occupancy (22/43/84%) does NOT move the ~110us fused floor;
//   ILP hacks hurt. R14 LESSON: the persistent test SPILLED (hoisted 16 regs
//   pushed demand past the 64 cap -> FETCH 290MB) -- theory untested.
// R15: clean persistent retry. EXACT r12 body (VGPR 40) in the loop, ZERO
//   hoists; only additions are the loop counter, s0, and scratch2 dbuf.
//   Pre-registered: ~55-80us => per-block fixed cost was the floor;
//   ~110us at no-spill => structural floor, declare next round.
__device__ __forceinline__ float ftanh(float x) {
  float t = __expf(2.0f * x);
  return 1.0f - 2.0f * __builtin_amdgcn_rcpf(t + 1.0f);
}
__device__ __forceinline__ float4v mfma16(short8 a, short8 b, float4v c) {
  return __builtin_amdgcn_mfma_f32_16x16x32_bf16(a, b, c, 0, 0, 0);
}

// ---- tile-major bf16 LDS layout: [tile m][kk-block of 32 cols][row 0..15][col&31]
// XOR bank swizzle: rotate the 32B sub-chunk by ((col>>5)^(row>>2))&3.
__device__ __forceinline__ int tmC(int row, int c) {        // chunk c = col/8, 0..31
  int base = ((row >> 4) * 8 + (c >> 2)) * 512 + (row & 15) * 32 + (c & 3) * 8;
  return base ^ ((((c >> 2) ^ (row >> 2)) & 3) << 4);
}
__device__ __forceinline__ int tmE(int row, int col) {      // single element
  int base = ((row >> 4) * 8 + (col >> 5)) * 512 + (row & 15) * 32 + (col & 31);
  return base ^ ((((col >> 5) ^ (row >> 2)) & 3) << 4);
}

#define A_TABLE { \
    {0,0,0,0,0,0,0,0,1}, \
    {1,0,0,0,0,0,0,0,0}, \
    {1.f/3,2.f/3,0,0,0,0,0,0,0}, \
    {0.2f,0.4f,0.4f,0,0,0,0,0,0}, \
    {0,0.2f,0.4f,0.4f,0,0,0,0,0}, \
    {0,0,0.2f,0.4f,0.4f,0,0,0,0}, \
    {0,0,0,0.2f,0.4f,0.4f,0,0,0}, \
    {0,0,0,0,0.25f,0.5f,0.25f,0,0}, \
    {0,0,0,0,0,1.f/3,1.f/3,1.f/3,0}, \
  }

// ---- prep_all (r8 proven): (blocks 0..143) stage Ww2t/Ww1p bf16;
//      (blocks 144..720) prep2a wave-per-output: V1/V2'/C0 -> vtab staging.
__global__ void prep_all(const float* __restrict__ Ww2,
                         const float* __restrict__ Ww1,
                         const float* __restrict__ Wm2,
                         const float* __restrict__ Wreg,
                         const float* __restrict__ bm2,
                         const float* __restrict__ breg,
                         unsigned short* __restrict__ ws,
                         float* __restrict__ vtab)
{
  const int b = blockIdx.x;
  if (b < 144) {
    int idx = b * 512 + threadIdx.x + 65536;   // 65536..139263
    if (idx < 131072) {
      int j = idx - 65536; int n = j >> 8, k = j & 255;
      ws[idx] = f2b(sane(Ww2[k * 256 + n]));
    } else {
      int j = idx - 131072; int n = j >> 5, k = j & 31;
      ws[idx] = (k < 8) ? f2b(sane(Ww1[k * 256 + n])) : (unsigned short)0;
    }
    return;
  }
  const float A[9][9] = A_TABLE;
  const int lane = threadIdx.x & 63;
  const int g = (b - 144) * 8 + (threadIdx.x >> 6);
  if (g < 4608) {
    int mat = (g >= 2304);              // 0: V1, 1: V2'
    int w = g - mat * 2304;
    int d = w >> 8, k = w & 255;
    float coef[9];
    #pragma unroll
    for (int dp = 0; dp < 9; ++dp) {
      if (!mat) {
        coef[dp] = A[dp][d];            // (A^T)[d][dp]
      } else {
        float s = 0.f;                  // (A^2)[dp][d]
        #pragma unroll
        for (int e = 0; e < 9; ++e) s += A[dp][e] * A[e][d];
        coef[dp] = s;
      }
    }
    const float* wm2row = Wm2 + (size_t)(mat * 256 + k) * 256;
    float acc = 0.f;
    #pragma unroll
    for (int it = 0; it < 4; ++it) {
      int h = lane + it * 64;           // coalesced across the wave
      float wp = 0.f;
      #pragma unroll
      for (int dp = 0; dp < 9; ++dp) wp = fmaf(coef[dp], Wreg[dp * 256 + h], wp);
      acc = fmaf(wp, wm2row[h], acc);
    }
    #pragma unroll
    for (int off = 32; off >= 1; off >>= 1) acc += __shfl_down(acc, off);
    if (lane == 0) vtab[5120 + g] = acc;
  } else if (g == 4608) {
    float c0 = 0.f;
    #pragma unroll
    for (int it = 0; it < 4; ++it) {
      int h = lane + it * 64;
      float cs = 0.f;
      #pragma unroll
      for (int d = 0; d < 9; ++d) cs += Wreg[d * 256 + h];
      c0 = fmaf(bm2[h], cs, c0);
    }
    #pragma unroll
    for (int off = 32; off >= 1; off >>= 1) c0 += __shfl_down(c0, off);
    if (lane == 0) vtab[9728] = c0 + breg[0];
  }
}

// ---- prep2b (r8 proven): wave-per-output.  U = A^T V1;
// final vtab: T1 @0 [9][256], Tw @2304 [9][256], C0' @4608
__global__ void prep2b_kernel(const float* __restrict__ Wm1,
                              const float* __restrict__ bm1,
                              float* __restrict__ vtab)
{
  const float A[9][9] = A_TABLE;
  const float* V1s = vtab + 5120;
  const float* V2s = vtab + 7424;
  const int lane = threadIdx.x & 63;
  const int g = blockIdx.x * 8 + (threadIdx.x >> 6);
  if (g < 4608) {
    int mat = (g >= 2304);              // 0: T1, 1: Tw
    int w = g - mat * 2304;
    int s = w >> 8, k = w & 255;
    const float* wm1row = Wm1 + (size_t)(mat * 256 + k) * 256;
    float acc = 0.f;
    #pragma unroll
    for (int it = 0; it < 4; ++it) {
      int h = lane + it * 64;
      float u = 0.f;
      #pragma unroll
      for (int d = 0; d < 9; ++d) u = fmaf(A[d][s], V1s[d * 256 + h], u);
      acc = fmaf(u, wm1row[h], acc);
    }
    #pragma unroll
    for (int off = 32; off >= 1; off >>= 1) acc += __shfl_down(acc, off);
    if (lane == 0) vtab[g] = acc + (mat ? V2s[s * 256 + k] : 0.f);
  } else if (g == 4608) {
    float c = 0.f;
    #pragma unroll
    for (int it = 0; it < 4; ++it) {
      int h = lane + it * 64;
      float vs = 0.f;
      #pragma unroll
      for (int d = 0; d < 9; ++d) vs += V1s[d * 256 + h];
      c = fmaf(bm1[h], vs, c);
    }
    #pragma unroll
    for (int off = 32; off >= 1; off >>= 1) c += __shfl_down(c, off);
    if (lane == 0) vtab[4608] = c + vtab[9728];
  }
}

// ---- prep3 (r8 proven): lags-branch LUT, 1024 blocks x 2 knots.
__global__ void prep3_lut(const float* __restrict__ Wl1,
                          const float* __restrict__ bl1,
                          const float* __restrict__ gbn,
                          const float* __restrict__ bbn,
                          const float* __restrict__ Wl2,
                          const float* __restrict__ bl2,
                          const float* __restrict__ vtab,   // T1 @0 [9][256]
                          float* __restrict__ lutf)         // [9][LUT_STRIDE]
{
  __shared__ float l0s[2][256];
  __shared__ float red[2][9][4];
  const int tid = threadIdx.x;        // 0..255
  const int b = blockIdx.x;           // 0..1023, knots b*2, b*2+1
  const float BNS = 0.99999500003750f;  // 1/sqrt(1+1e-5)
  {
    float w = Wl1[tid], a = bl1[tid], g = gbn[tid] * BNS, q = bbn[tid];
    #pragma unroll
    for (int j = 0; j < 2; ++j) {
      float s = SLO + (float)(b * 2 + j) * 0.0078125f;   // 16/2048 exact
      l0s[j][tid] = fmaf(ftanh(fmaf(s, w, a)), g, q);
    }
  }
  __syncthreads();
  float z0 = bl2[tid], z1 = z0;
  #pragma unroll 8
  for (int k = 0; k < 256; ++k) {
    float wv = Wl2[k * 256 + tid];          // coalesced across tid; L2-hot
    z0 = fmaf(l0s[0][k], wv, z0);
    z1 = fmaf(l0s[1][k], wv, z1);
  }
  float t0 = ftanh(z0), t1 = ftanh(z1);
  const int lane = tid & 63, w4 = tid >> 6;
  for (int d = 0; d < 9; ++d) {
    float T1h = vtab[d * 256 + tid];
    float v0 = t0 * T1h, v1 = t1 * T1h;
    #pragma unroll
    for (int off = 32; off >= 1; off >>= 1) {
      v0 += __shfl_down(v0, off);
      v1 += __shfl_down(v1, off);
    }
    if (lane == 0) { red[0][d][w4] = v0; red[1][d][w4] = v1; }
  }
  __syncthreads();
  if (tid < 18) {
    int j = tid / 9, d = tid - j * 9;
    float v = red[j][d][0] + red[j][d][1] + red[j][d][2] + red[j][d][3];
    lutf[d * LUT_STRIDE + (b * 2 + j)] = v;
  }
}

// Fused (v15): PERSISTENT retry, ZERO hoists. Exact r12 per-group body
// (VGPR 40 proven) inside an 8-iteration loop. Only new state: it, s0, sc2.
// LDS race analysis (2 barriers/iter):
//  - sT: PhaseB(i+1) writes happen after bar2(i); gemm(i) reads before bar2(i). SAFE.
//  - scratch: write pre-bar2(i), read post-bar2(i); next write post-bar1(i+1). SAFE.
//  - scratch2: post-bar2(i) read races pre-bar1(i+1) write -> dbuf by (it&1).
__global__ void __launch_bounds__(NTHREADS, 1)
fused_kernel(const float* __restrict__ lags,
             const float* __restrict__ weather,
             const float* __restrict__ bw1,
             const float* __restrict__ bw2,
             const unsigned short* __restrict__ ws,
             const float* __restrict__ vtab,
             float* __restrict__ out)
{
  __shared__ __align__(16) unsigned short sBuf[SBUF_SHORTS];  // 75,904 B
  unsigned short* sT = sBuf;
  float* scratch  = (float*)(sBuf + 36864);        // 256 f32 wave partials
  float* scratch2 = (float*)(sBuf + 36864 + 512);  // 2 x 144 f32 LUT partials

  const int tid = threadIdx.x;          // 0..1023
  const int wave = tid >> 6;            // 0..15
  const int lane16 = tid & 15;
  const int g4 = (tid >> 4) & 3;

  const float* lutf = (const float*)ws;            // 9 x LUT_STRIDE f32
  const unsigned short* Ww2t = ws + 65536;
  const unsigned short* Ww1p = ws + 131072;

  const int c = wave * 16 + lane16;     // wave's ONE output column (0..255)

  #pragma unroll 1
  for (int it = 0; it < NGRP; ++it) {
    const int s0 = (blockIdx.x * NGRP + it) * GSAMP;
    float* sc2 = scratch2 + (it & 1) * 144;

    // ---- lag-LUT: threads 0..143, one (sample, d) each ----
    if (tid < 144) {
      int samp = tid / 9, d = tid - samp * 9;
      float x = lags[(s0 + samp) * NLAGS + d];
      float tp = (x - SLO) * KINV;
      tp = fminf(fmaxf(tp, 0.0f), (float)(NK - 2) + 0.999f);
      int j = (int)tp; float fr = tp - (float)j;
      const float* row = lutf + d * LUT_STRIDE;
      float lo = row[j], hi = row[j + 1];
      sc2[tid] = fmaf(fr, hi - lo, lo);   // samp*9 + d
    }

    // ---- Phase B: w0 = tanh(weather @ Ww1 + bw1) -> sT (K pad 8->32) ----
    {
      short8 bf = *(const short8*)(Ww1p + c * 32 + g4 * 8);
      float bia = bw1[c];
      #pragma unroll
      for (int m = 0; m < 9; ++m) {       // m = lag tile; row-in-tile = lane16
        S8 a8;
        if (g4 == 0) {
          const float* wp = weather + (size_t)(s0 + lane16) * 72 + m * 8;
          float4v x0 = *(const float4v*)(wp);
          float4v x1 = *(const float4v*)(wp + 4);
          a8.v = (short8){0,0,0,0,0,0,0,0};
          unsigned int p0 = pkbf16(x0[0], x0[1]), p1 = pkbf16(x0[2], x0[3]);
          unsigned int p2 = pkbf16(x1[0], x1[1]), p3 = pkbf16(x1[2], x1[3]);
          a8.u[0] = (unsigned short)p0; a8.u[1] = (unsigned short)(p0 >> 16);
          a8.u[2] = (unsigned short)p1; a8.u[3] = (unsigned short)(p1 >> 16);
          a8.u[4] = (unsigned short)p2; a8.u[5] = (unsigned short)(p2 >> 16);
          a8.u[6] = (unsigned short)p3; a8.u[7] = (unsigned short)(p3 >> 16);
        } else {
          a8.v = (short8){0,0,0,0,0,0,0,0};
        }
        float4v zz = {0.f, 0.f, 0.f, 0.f};
        float4v ac = mfma16(a8.v, bf, zz);
        float t0 = ftanh(ac[0] + bia), t1 = ftanh(ac[1] + bia);
        float t2 = ftanh(ac[2] + bia), t3 = ftanh(ac[3] + bia);
        unsigned int p01 = pkbf16(t0, t1);
        unsigned int p23 = pkbf16(t2, t3);
        int r0 = m * 16 + g4 * 4;         // C/D: col=lane&15, row=(lane>>4)*4+i
        sT[tmE(r0 + 0, c)] = (unsigned short)p01;
        sT[tmE(r0 + 1, c)] = (unsigned short)(p01 >> 16);
        sT[tmE(r0 + 2, c)] = (unsigned short)p23;
        sT[tmE(r0 + 3, c)] = (unsigned short)(p23 >> 16);
      }
    }
    __syncthreads();   // bar1: sT = w0 and sc2 published

    float P[4] = {0.f, 0.f, 0.f, 0.f};  // partial outputs, samples g4*4+i

    // ---- gemm-sW (K=256): w1 = tanh(w0@Ww2+bw2); P += <w1, Tw> ----
    {
      float4v acc[9];
      #pragma unroll
      for (int m = 0; m < 9; ++m) {
        float4v z = {0.f,0.f,0.f,0.f};
        acc[m] = z;
      }
      #pragma unroll
      for (int kk = 0; kk < 8; ++kk) {
        short8 b0 = *(const short8*)(Ww2t + c * 256 + kk * 32 + g4 * 8);
        #pragma unroll
        for (int m = 0; m < 9; ++m) {
          short8 a = *(const short8*)(sT + tmC(m * 16 + lane16, kk * 4 + g4));
          acc[m] = mfma16(a, b0, acc[m]);
        }
      }
      float twc[9];
      #pragma unroll
      for (int m = 0; m < 9; ++m) twc[m] = vtab[2304 + m * 256 + c];
      float bia = bw2[c];
      #pragma unroll
      for (int m = 0; m < 9; ++m) {
        #pragma unroll
        for (int i = 0; i < 4; ++i) {
          float t0 = ftanh(acc[m][i] + bia);   // w1, f32 (never quantized)
          P[i] = fmaf(t0, twc[m], P[i]);
        }
      }
    }

    // ---- reduce: cols (shfl within lane16 groups) then waves (scratch) ----
    #pragma unroll
    for (int off = 8; off >= 1; off >>= 1) {
      #pragma unroll
      for (int i = 0; i < 4; ++i) P[i] += __shfl_down(P[i], off, 16);
    }
    if (lane16 == 0) {
      #pragma unroll
      for (int i = 0; i < 4; ++i) scratch[wave * 16 + g4 * 4 + i] = P[i];
    }
    __syncthreads();   // bar2: scratch published
    if (tid < GSAMP) {
      float sum = 0.f;
      #pragma unroll
      for (int w = 0; w < 16; ++w) sum += scratch[w * 16 + tid];
      float lsum = 0.f;
      #pragma unroll
      for (int d = 0; d < 9; ++d) lsum += sc2[tid * 9 + d];
      out[s0 + tid] = sum + lsum + vtab[4608];   // + C0'
    }
  }
}

extern "C" void kernel_launch(void* const* d_in, const int* in_sizes, int n_in,
                              void* d_out, int out_size, void* d_ws, size_t ws_size,
                              hipStream_t stream) {
  const float* lags    = (const float*)d_in[0];
  const float* weather = (const float*)d_in[1];
  const float* Wl1     = (const float*)d_in[2];
  const float* bl1     = (const float*)d_in[3];
  const float* gbn     = (const float*)d_in[4];
  const float* bbn     = (const float*)d_in[5];
  const float* Wl2     = (const float*)d_in[6];
  const float* bl2     = (const float*)d_in[7];
  const float* Ww1     = (const float*)d_in[8];
  const float* bw1     = (const float*)d_in[9];
  const float* Ww2     = (const float*)d_in[10];
  const float* bw2     = (const float*)d_in[11];
  const float* Wm1     = (const float*)d_in[12];
  const float* bm1     = (const float*)d_in[13];
  const float* Wm2     = (const float*)d_in[14];
  const float* bm2     = (const float*)d_in[15];
  const float* Wreg    = (const float*)d_in[16];
  const float* breg    = (const float*)d_in[17];
  unsigned short* ws = (unsigned short*)d_ws;
  float* vtab = (float*)(ws + 139264);    // byte offset 278,528 (16B-aligned)
  float* lutf = (float*)ws;               // f32 LUT in dead Wl2t region (128KB)

  // r8-proven prep chain
  prep_all<<<721, 512, 0, stream>>>(Ww2, Ww1, Wm2, Wreg, bm2, breg, ws, vtab);
  prep2b_kernel<<<577, 512, 0, stream>>>(Wm1, bm1, vtab);
  prep3_lut<<<1024, 256, 0, stream>>>(Wl1, bl1, gbn, bbn, Wl2, bl2, vtab, lutf);

  // persistent fused: 256 blocks (1/CU), 8 groups each
  fused_kernel<<<NBLK, NTHREADS, 0, stream>>>(
      lags, weather, bw1, bw2, ws, vtab, (float*)d_out);
}

// Round 16
// 214.435 us; speedup vs baseline: 1.8442x; 1.8442x over previous
//
#include <hip/hip_runtime.h>

typedef __attribute__((ext_vector_type(8))) short short8;
typedef __attribute__((ext_vector_type(4))) float float4v;

#define NLAGS 9
#define HID 256
#define GSAMP 16
#define NTHREADS 512
// ONE tile buffer (w0) + 128 f32 wave-partials + 144 f32 lag-LUT partials
#define SBUF_SHORTS (36864 + 256 + 288)   // 74,816 B

// LUT geometry: 9 rows (per lag-slot d), 2048 knots over [-8, 8]
#define NK 2048
#define LUT_STRIDE 2056                   // padded row stride (floats)
#define SLO -8.0f
#define KINV 128.0f                       // NK / 16

union S8 { short8 v; unsigned short u[8]; };

__device__ __forceinline__ unsigned short f2b(float f) {
  union { float f; unsigned int i; } c; c.f = f;
  return (unsigned short)((c.i + 0x7FFFu + ((c.i >> 16) & 1u)) >> 16);  // RNE
}
__device__ __forceinline__ float sane(float x) {
  return (__builtin_isfinite(x) && fabsf(x) < 1e30f) ? x : 0.0f;
}
// HW packed f32->bf16 (RNE), 1 VALU op for 2 conversions
__device__ __forceinline__ unsigned int pkbf16(float lo, float hi) {
  unsigned int r;
  asm("v_cvt_pk_bf16_f32 %0, %1, %2" : "=v"(r) : "v"(lo), "v"(hi));
  return r;
}
// ===================== SESSION JOURNAL (r0-r15) =====================
// BLACKLIST (r8-r10 bisect): bias-init-in-MFMA-C and exp2f-tanh broke
//   correctness. BLACKLIST (R10): hipLaunchCooperativeKernel -> silent
//   non-exec under graph capture (absmax 1.0).
// REGISTER MODEL (R1-R6): compiler arch cap scales as 256/min_waves at
//   512 threads; HW occupancy = floor(512/(arch+agpr)) waves/SIMD (AGPRs
//   hidden from VGPR_Count but count against the unified file). Spill iff
//   demand > cap (watch WRITE_SIZE/FETCH_SIZE balloon).
// WINS: r0 single-buffer LDS reorder; R7 l-branch -> 9x1D f32 LUT
//   (entire lags MLP is per-(sample,lag) scalar fn; 200->112us, absmax
//   unchanged); R8 prep3 regrid 256x8 -> 1024x2 (latency-bound fix).
// CLOSED LINES (each falsified by counters):
//   - Occupancy: fused ~110-120us flat at 22%/43%/84% occ (r8/r12/r13).
//   - ILP-for-regs hacks (unroll-1 + opaque ptr): always net-negative
//     (R6 237us, R13 133us).
//   - Bigger tile GSAMP=32: arch cap spill (R9).
//   - Persistent blocks: compiler LICM hoists loop-invariant loads ->
//     spill even with zero manual hoists (R14/R15). Defeating LICM
//     needs the banned hacks. Lever closed.
//   - Launch-count merges: cooperative banned (R10); algebraic prep_A
//     merge worked but was ~equal-or-slower (R11, noise +-10-15us).
// STRUCTURAL FLOOR: fused ~110-120us (phase-serial VALU->bar->MFMA at
//   2-barrier cadence); prep chain + dispatch gaps ~90us. Best verified
//   total: THIS configuration (r8) = 213us.
// ====================================================================
__device__ __forceinline__ float ftanh(float x) {
  float t = __expf(2.0f * x);
  return 1.0f - 2.0f * __builtin_amdgcn_rcpf(t + 1.0f);
}
__device__ __forceinline__ float4v mfma16(short8 a, short8 b, float4v c) {
  return __builtin_amdgcn_mfma_f32_16x16x32_bf16(a, b, c, 0, 0, 0);
}

// ---- tile-major bf16 LDS layout: [tile m][kk-block of 32 cols][row 0..15][col&31]
// XOR bank swizzle: rotate the 32B sub-chunk by ((col>>5)^(row>>2))&3.
__device__ __forceinline__ int tmC(int row, int c) {        // chunk c = col/8, 0..31
  int base = ((row >> 4) * 8 + (c >> 2)) * 512 + (row & 15) * 32 + (c & 3) * 8;
  return base ^ ((((c >> 2) ^ (row >> 2)) & 3) << 4);
}
__device__ __forceinline__ int tmE(int row, int col) {      // single element
  int base = ((row >> 4) * 8 + (col >> 5)) * 512 + (row & 15) * 32 + (col & 31);
  return base ^ ((((col >> 5) ^ (row >> 2)) & 3) << 4);
}

#define A_TABLE { \
    {0,0,0,0,0,0,0,0,1}, \
    {1,0,0,0,0,0,0,0,0}, \
    {1.f/3,2.f/3,0,0,0,0,0,0,0}, \
    {0.2f,0.4f,0.4f,0,0,0,0,0,0}, \
    {0,0.2f,0.4f,0.4f,0,0,0,0,0}, \
    {0,0,0.2f,0.4f,0.4f,0,0,0,0}, \
    {0,0,0,0.2f,0.4f,0.4f,0,0,0}, \
    {0,0,0,0,0.25f,0.5f,0.25f,0,0}, \
    {0,0,0,0,0,1.f/3,1.f/3,1.f/3,0}, \
  }

// ---- prep_all: (blocks 0..143) stage Ww2t/Ww1p bf16; (144..720) prep2a
//      wave-per-output: V1/V2'/C0 -> vtab staging.
// ws (shorts): [0..65535] f32 LUT region (prep3); Ww2t @65536; Ww1p @131072.
// vtab staging (f32): V1 @5120 [9][256], V2' @7424 [9][256], C0 @9728
__global__ void prep_all(const float* __restrict__ Ww2,
                         const float* __restrict__ Ww1,
                         const float* __restrict__ Wm2,
                         const float* __restrict__ Wreg,
                         const float* __restrict__ bm2,
                         const float* __restrict__ breg,
                         unsigned short* __restrict__ ws,
                         float* __restrict__ vtab)
{
  const int b = blockIdx.x;
  if (b < 144) {
    int idx = b * 512 + threadIdx.x + 65536;   // 65536..139263
    if (idx < 131072) {
      int j = idx - 65536; int n = j >> 8, k = j & 255;
      ws[idx] = f2b(sane(Ww2[k * 256 + n]));
    } else {
      int j = idx - 131072; int n = j >> 5, k = j & 31;
      ws[idx] = (k < 8) ? f2b(sane(Ww1[k * 256 + n])) : (unsigned short)0;
    }
    return;
  }
  // ---- prep2a: one wave per output element ----
  const float A[9][9] = A_TABLE;
  const int lane = threadIdx.x & 63;
  const int g = (b - 144) * 8 + (threadIdx.x >> 6);
  if (g < 4608) {
    int mat = (g >= 2304);              // 0: V1, 1: V2'
    int w = g - mat * 2304;
    int d = w >> 8, k = w & 255;
    float coef[9];
    #pragma unroll
    for (int dp = 0; dp < 9; ++dp) {
      if (!mat) {
        coef[dp] = A[dp][d];            // (A^T)[d][dp]
      } else {
        float s = 0.f;                  // (A^2)[dp][d]
        #pragma unroll
        for (int e = 0; e < 9; ++e) s += A[dp][e] * A[e][d];
        coef[dp] = s;
      }
    }
    const float* wm2row = Wm2 + (size_t)(mat * 256 + k) * 256;
    float acc = 0.f;
    #pragma unroll
    for (int it = 0; it < 4; ++it) {
      int h = lane + it * 64;           // coalesced across the wave
      float wp = 0.f;
      #pragma unroll
      for (int dp = 0; dp < 9; ++dp) wp = fmaf(coef[dp], Wreg[dp * 256 + h], wp);
      acc = fmaf(wp, wm2row[h], acc);
    }
    #pragma unroll
    for (int off = 32; off >= 1; off >>= 1) acc += __shfl_down(acc, off);
    if (lane == 0) vtab[5120 + g] = acc;
  } else if (g == 4608) {
    float c0 = 0.f;
    #pragma unroll
    for (int it = 0; it < 4; ++it) {
      int h = lane + it * 64;
      float cs = 0.f;
      #pragma unroll
      for (int d = 0; d < 9; ++d) cs += Wreg[d * 256 + h];
      c0 = fmaf(bm2[h], cs, c0);
    }
    #pragma unroll
    for (int off = 32; off >= 1; off >>= 1) c0 += __shfl_down(c0, off);
    if (lane == 0) vtab[9728] = c0 + breg[0];
  }
}

// ---- prep2b: wave-per-output.  U = A^T V1;
// final vtab: T1 @0 [9][256], Tw @2304 [9][256], C0' @4608
__global__ void prep2b_kernel(const float* __restrict__ Wm1,
                              const float* __restrict__ bm1,
                              float* __restrict__ vtab)
{
  const float A[9][9] = A_TABLE;
  const float* V1s = vtab + 5120;
  const float* V2s = vtab + 7424;
  const int lane = threadIdx.x & 63;
  const int g = blockIdx.x * 8 + (threadIdx.x >> 6);
  if (g < 4608) {
    int mat = (g >= 2304);              // 0: T1, 1: Tw
    int w = g - mat * 2304;
    int s = w >> 8, k = w & 255;
    const float* wm1row = Wm1 + (size_t)(mat * 256 + k) * 256;
    float acc = 0.f;
    #pragma unroll
    for (int it = 0; it < 4; ++it) {
      int h = lane + it * 64;
      float u = 0.f;
      #pragma unroll
      for (int d = 0; d < 9; ++d) u = fmaf(A[d][s], V1s[d * 256 + h], u);
      acc = fmaf(u, wm1row[h], acc);
    }
    #pragma unroll
    for (int off = 32; off >= 1; off >>= 1) acc += __shfl_down(acc, off);
    if (lane == 0) vtab[g] = acc + (mat ? V2s[s * 256 + k] : 0.f);
  } else if (g == 4608) {
    float c = 0.f;
    #pragma unroll
    for (int it = 0; it < 4; ++it) {
      int h = lane + it * 64;
      float vs = 0.f;
      #pragma unroll
      for (int d = 0; d < 9; ++d) vs += V1s[d * 256 + h];
      c = fmaf(bm1[h], vs, c);
    }
    #pragma unroll
    for (int off = 32; off >= 1; off >>= 1) c += __shfl_down(c, off);
    if (lane == 0) vtab[4608] = c + vtab[9728];
  }
}

// ---- prep3: build the lags-branch LUT.  Per lag-slot d, scalar function:
//   f_d(x) = sum_h tanh( l0(x) @ Wl2 + bl2 )[h] * T1[d,h]
// 1024 blocks x 2 knots (R8 regrid: 4 blocks/CU -> TLP hides the 256-step
// L2-load chain).
__global__ void prep3_lut(const float* __restrict__ Wl1,
                          const float* __restrict__ bl1,
                          const float* __restrict__ gbn,
                          const float* __restrict__ bbn,
                          const float* __restrict__ Wl2,
                          const float* __restrict__ bl2,
                          const float* __restrict__ vtab,   // T1 @0 [9][256]
                          float* __restrict__ lutf)         // [9][LUT_STRIDE]
{
  __shared__ float l0s[2][256];
  __shared__ float red[2][9][4];
  const int tid = threadIdx.x;        // 0..255
  const int b = blockIdx.x;           // 0..1023, knots b*2, b*2+1
  const float BNS = 0.99999500003750f;  // 1/sqrt(1+1e-5)
  {
    float w = Wl1[tid], a = bl1[tid], g = gbn[tid] * BNS, q = bbn[tid];
    #pragma unroll
    for (int j = 0; j < 2; ++j) {
      float s = SLO + (float)(b * 2 + j) * 0.0078125f;   // 16/2048 exact
      l0s[j][tid] = fmaf(ftanh(fmaf(s, w, a)), g, q);
    }
  }
  __syncthreads();
  float z0 = bl2[tid], z1 = z0;
  #pragma unroll 8
  for (int k = 0; k < 256; ++k) {
    float wv = Wl2[k * 256 + tid];          // coalesced across tid; L2-hot
    z0 = fmaf(l0s[0][k], wv, z0);
    z1 = fmaf(l0s[1][k], wv, z1);
  }
  float t0 = ftanh(z0), t1 = ftanh(z1);
  const int lane = tid & 63, w4 = tid >> 6;
  for (int d = 0; d < 9; ++d) {
    float T1h = vtab[d * 256 + tid];
    float v0 = t0 * T1h, v1 = t1 * T1h;
    #pragma unroll
    for (int off = 32; off >= 1; off >>= 1) {
      v0 += __shfl_down(v0, off);
      v1 += __shfl_down(v1, off);
    }
    if (lane == 0) { red[0][d][w4] = v0; red[1][d][w4] = v1; }
  }
  __syncthreads();
  if (tid < 18) {
    int j = tid / 9, d = tid - j * 9;
    float v = red[j][d][0] + red[j][d][1] + red[j][d][2] + red[j][d][3];
    lutf[d * LUT_STRIDE + (b * 2 + j)] = v;
  }
}

// Fused (r8's v8, the best verified config): lag-LUT lerps | Phase B (w0->sT)
// | bar | gemm-sW | reduce | out.  512 threads, 2 cols/wave, GSAMP=16.
__global__ void __launch_bounds__(NTHREADS, 2)
fused_kernel(const float* __restrict__ lags,
             const float* __restrict__ weather,
             const float* __restrict__ bw1,
             const float* __restrict__ bw2,
             const unsigned short* __restrict__ ws,
             const float* __restrict__ vtab,
             float* __restrict__ out)
{
  __shared__ __align__(16) unsigned short sBuf[SBUF_SHORTS];  // 74,816 B
  unsigned short* sT = sBuf;
  float* scratch  = (float*)(sBuf + 36864);        // 128 f32 wave partials
  float* scratch2 = (float*)(sBuf + 36864 + 256);  // 144 f32 lag-LUT partials

  const int tid = threadIdx.x;
  const int wave = tid >> 6;
  const int lane16 = tid & 15;
  const int g4 = (tid >> 4) & 3;
  const int s0 = blockIdx.x * GSAMP;

  const float* lutf = (const float*)ws;            // 9 x LUT_STRIDE f32
  const unsigned short* Ww2t = ws + 65536;
  const unsigned short* Ww1p = ws + 131072;

  const int c0 = wave * 32 + lane16;       // wave's two output columns
  const int c1 = wave * 32 + 16 + lane16;

  // ---- lag-LUT: threads 0..143, one (sample, d) each ----
  if (tid < 144) {
    int samp = tid / 9, d = tid - samp * 9;
    float x = lags[(s0 + samp) * NLAGS + d];
    float tp = (x - SLO) * KINV;
    tp = fminf(fmaxf(tp, 0.0f), (float)(NK - 2) + 0.999f);
    int j = (int)tp; float fr = tp - (float)j;
    const float* row = lutf + d * LUT_STRIDE;
    float lo = row[j], hi = row[j + 1];
    scratch2[tid] = fmaf(fr, hi - lo, lo);   // samp*9 + d
  }

  // ---- Phase B: w0 = tanh(weather @ Ww1 + bw1) -> sT (K pad 8->32) ----
  {
    short8 bf0 = *(const short8*)(Ww1p + c0 * 32 + g4 * 8);
    short8 bf1 = *(const short8*)(Ww1p + c1 * 32 + g4 * 8);
    float bia0 = bw1[c0], bia1 = bw1[c1];
    #pragma unroll
    for (int m = 0; m < 9; ++m) {         // m = lag tile; row-in-tile = lane16
      S8 a8;
      if (g4 == 0) {
        const float* wp = weather + (size_t)(s0 + lane16) * 72 + m * 8;
        float4v x0 = *(const float4v*)(wp);
        float4v x1 = *(const float4v*)(wp + 4);
        a8.v = (short8){0,0,0,0,0,0,0,0};
        unsigned int p0 = pkbf16(x0[0], x0[1]), p1 = pkbf16(x0[2], x0[3]);
        unsigned int p2 = pkbf16(x1[0], x1[1]), p3 = pkbf16(x1[2], x1[3]);
        a8.u[0] = (unsigned short)p0; a8.u[1] = (unsigned short)(p0 >> 16);
        a8.u[2] = (unsigned short)p1; a8.u[3] = (unsigned short)(p1 >> 16);
        a8.u[4] = (unsigned short)p2; a8.u[5] = (unsigned short)(p2 >> 16);
        a8.u[6] = (unsigned short)p3; a8.u[7] = (unsigned short)(p3 >> 16);
      } else {
        a8.v = (short8){0,0,0,0,0,0,0,0};
      }
      float4v zz = {0.f, 0.f, 0.f, 0.f};
      float4v ac0 = mfma16(a8.v, bf0, zz);
      float4v ac1 = mfma16(a8.v, bf1, zz);
      #pragma unroll
      for (int i = 0; i < 4; ++i) {
        int row = m * 16 + g4 * 4 + i;    // C/D: col=lane&15, row=(lane>>4)*4+i
        unsigned int p = pkbf16(ftanh(ac0[i] + bia0), ftanh(ac1[i] + bia1));
        sT[tmE(row, c0)] = (unsigned short)p;
        sT[tmE(row, c1)] = (unsigned short)(p >> 16);
      }
    }
  }
  __syncthreads();   // B1: sT = w0 and scratch2 published

  float P[4] = {0.f, 0.f, 0.f, 0.f};   // per-lane partial outputs, samples g4*4+i

  // ---- gemm-sW (K=256): w1 = tanh(w0@Ww2+bw2); epilogue: P += <w1, Tw> ----
  {
    float4v acc0[9], acc1[9];
    #pragma unroll
    for (int m = 0; m < 9; ++m) {
      float4v z = {0.f,0.f,0.f,0.f};
      acc0[m] = z; acc1[m] = z;
    }
    #pragma unroll
    for (int kk = 0; kk < 8; ++kk) {
      short8 b0 = *(const short8*)(Ww2t + c0 * 256 + kk * 32 + g4 * 8);
      short8 b1 = *(const short8*)(Ww2t + c1 * 256 + kk * 32 + g4 * 8);
      #pragma unroll
      for (int m = 0; m < 9; ++m) {
        short8 a = *(const short8*)(sT + tmC(m * 16 + lane16, kk * 4 + g4));
        acc0[m] = mfma16(a, b0, acc0[m]);
        acc1[m] = mfma16(a, b1, acc1[m]);
      }
    }
    float twc0[9], twc1[9];
    #pragma unroll
    for (int m = 0; m < 9; ++m) {
      twc0[m] = vtab[2304 + m * 256 + c0];   // Tw[lag=m][col]
      twc1[m] = vtab[2304 + m * 256 + c1];
    }
    float bia0 = bw2[c0], bia1 = bw2[c1];
    #pragma unroll
    for (int m = 0; m < 9; ++m) {
      #pragma unroll
      for (int i = 0; i < 4; ++i) {
        float t0 = ftanh(acc0[m][i] + bia0);   // w1, f32 (never quantized)
        float t1 = ftanh(acc1[m][i] + bia1);
        P[i] = fmaf(t0, twc0[m], P[i]);
        P[i] = fmaf(t1, twc1[m], P[i]);
      }
    }
  }

  // ---- reduce: cols (shfl within lane16 groups) then waves (scratch) ----
  #pragma unroll
  for (int off = 8; off >= 1; off >>= 1) {
    #pragma unroll
    for (int i = 0; i < 4; ++i) P[i] += __shfl_down(P[i], off, 16);
  }
  if (lane16 == 0) {
    #pragma unroll
    for (int i = 0; i < 4; ++i) scratch[wave * 16 + g4 * 4 + i] = P[i];
  }
  __syncthreads();   // B2: scratch published
  if (tid < GSAMP) {
    float sum = 0.f;
    #pragma unroll
    for (int w = 0; w < 8; ++w) sum += scratch[w * 16 + tid];
    float lsum = 0.f;
    #pragma unroll
    for (int d = 0; d < 9; ++d) lsum += scratch2[tid * 9 + d];
    out[s0 + tid] = sum + lsum + vtab[4608];   // + C0'
  }
}

extern "C" void kernel_launch(void* const* d_in, const int* in_sizes, int n_in,
                              void* d_out, int out_size, void* d_ws, size_t ws_size,
                              hipStream_t stream) {
  const float* lags    = (const float*)d_in[0];
  const float* weather = (const float*)d_in[1];
  const float* Wl1     = (const float*)d_in[2];
  const float* bl1     = (const float*)d_in[3];
  const float* gbn     = (const float*)d_in[4];
  const float* bbn     = (const float*)d_in[5];
  const float* Wl2     = (const float*)d_in[6];
  const float* bl2     = (const float*)d_in[7];
  const float* Ww1     = (const float*)d_in[8];
  const float* bw1     = (const float*)d_in[9];
  const float* Ww2     = (const float*)d_in[10];
  const float* bw2     = (const float*)d_in[11];
  const float* Wm1     = (const float*)d_in[12];
  const float* bm1     = (const float*)d_in[13];
  const float* Wm2     = (const float*)d_in[14];
  const float* bm2     = (const float*)d_in[15];
  const float* Wreg    = (const float*)d_in[16];
  const float* breg    = (const float*)d_in[17];
  unsigned short* ws = (unsigned short*)d_ws;
  float* vtab = (float*)(ws + 139264);    // byte offset 278,528 (16B-aligned)
  float* lutf = (float*)ws;               // f32 LUT in dead Wl2t region (128KB)

  // r8-proven prep chain: staging+V1/V2'/C0 -> T1/Tw/C0' -> lag LUT
  prep_all<<<721, 512, 0, stream>>>(Ww2, Ww1, Wm2, Wreg, bm2, breg, ws, vtab);
  prep2b_kernel<<<577, 512, 0, stream>>>(Wm1, bm1, vtab);
  prep3_lut<<<1024, 256, 0, stream>>>(Wl1, bl1, gbn, bbn, Wl2, bl2, vtab, lutf);

  const int nblocks = 32768 / GSAMP;  // 2048
  fused_kernel<<<nblocks, NTHREADS, 0, stream>>>(
      lags, weather, bw1, bw2, ws, vtab, (float*)d_out);
}